// Round 2
// 856.449 us; speedup vs baseline: 1.8144x; 1.8144x over previous
//
#include <hip/hip_runtime.h>

#define T_DIM 4096
#define C_DIM 2048
#define K_DIM 2048

typedef __bf16 bf16x8 __attribute__((ext_vector_type(8)));
typedef float f32x4 __attribute__((ext_vector_type(4)));

__device__ __forceinline__ unsigned short f2bf(float f) {
  union { float f; unsigned int i; } x;
  x.f = f;
  unsigned int r = x.i + 0x7fffu + ((x.i >> 16) & 1u);  // round-to-nearest-even
  return (unsigned short)(r >> 16);
}

// async global->LDS, 16B per lane; LDS dest = wave-uniform base + lane*16
#define GLD16(gsrc, ldst)                                                   \
  __builtin_amdgcn_global_load_lds(                                         \
      (const __attribute__((address_space(1))) unsigned int*)(gsrc),        \
      (__attribute__((address_space(3))) unsigned int*)(ldst), 16, 0, 0)

// ---------------- W (K x N) fp32 -> Wt (N x K) bf16 ----------------
__global__ __launch_bounds__(256) void transpose_w(const float* __restrict__ W,
                                                   unsigned short* __restrict__ Wt) {
  __shared__ float tile[64][68];  // +4 pad
  const int c0 = blockIdx.x * 64;  // n
  const int r0 = blockIdx.y * 64;  // k
  const int tid = threadIdx.x;
#pragma unroll
  for (int i = 0; i < 4; ++i) {
    int s = tid + i * 256;  // 0..1023 float4 slots (64 rows x 16 slots)
    int r = s >> 4, c4 = (s & 15) * 4;
    *(float4*)&tile[r][c4] = *(const float4*)&W[(size_t)(r0 + r) * C_DIM + c0 + c4];
  }
  __syncthreads();
#pragma unroll
  for (int i = 0; i < 2; ++i) {
    int s = tid + i * 256;  // 0..511: 64 n-rows x 8 slots of 8 bf16
    int n = s >> 3, k8 = (s & 7) * 8;
    __align__(16) unsigned short tmp[8];
#pragma unroll
    for (int j = 0; j < 8; ++j) tmp[j] = f2bf(tile[k8 + j][n]);
    *(uint4*)&Wt[(size_t)(c0 + n) * K_DIM + r0 + k8] = *(uint4*)tmp;
  }
}

// ---------------- X fp32 -> Xb bf16 (one pass, RNE identical to f2bf staging) ----------------
__global__ __launch_bounds__(256) void cvt_x(const float* __restrict__ X,
                                             unsigned short* __restrict__ Xb) {
  size_t base = (size_t)blockIdx.x * 2048 + (size_t)threadIdx.x * 8;
  float4 a = *(const float4*)&X[base];
  float4 b = *(const float4*)&X[base + 4];
  __align__(16) unsigned short t[8];
  t[0] = f2bf(a.x); t[1] = f2bf(a.y); t[2] = f2bf(a.z); t[3] = f2bf(a.w);
  t[4] = f2bf(b.x); t[5] = f2bf(b.y); t[6] = f2bf(b.z); t[7] = f2bf(b.w);
  *(uint4*)&Xb[base] = *(const uint4*)t;
}

// ------- fused GEMM + rope + relu + bias + tanh + GroupNorm + transpose -------
// B (Wt) bf16 [n][k] staged via global_load_lds. A either:
//   ABF16=true : bf16 Xb [m][k] staged via global_load_lds (needs 42MB workspace)
//   ABF16=false: fp32 X  [m][k] staged via global_load_lds, cvt->bf16 at frag read
// BK=64, single LDS buffer, 2 barriers/K-step; staging LDS unioned with epilogue lsO.
template <bool ABF16>
__global__ __launch_bounds__(256, 3) void gemm_fused(const void* __restrict__ Av,
                                                     const unsigned short* __restrict__ Wt,
                                                     const float* __restrict__ hhb,
                                                     const float* __restrict__ gnw,
                                                     const float* __restrict__ gnb,
                                                     float* __restrict__ out) {
  constexpr int SMEM_BYTES = ABF16 ? 34816 : 49152;
  __shared__ __align__(16) char smem[SMEM_BYTES];
  // bf16 path: lsA bf16 [128][64] @0 (16KB), lsB @16KB (16KB)
  // fp32 path: lsAf fp32 [128][64] @0 (32KB), lsB @32KB (16KB)
  unsigned short* lsA = (unsigned short*)smem;
  float* lsAf = (float*)smem;
  unsigned short* lsB = (unsigned short*)(smem + (ABF16 ? 16384 : 32768));
  float(*lsO)[68] = (float(*)[68])smem;  // epilogue reuse, 34.8KB

  const int tid = threadIdx.x;
  const int wave = tid >> 6;
  const int lane = tid & 63;
  const int quad = lane >> 4;
  const int l16 = lane & 15;
  const int wm = wave >> 1, wn = wave & 1;

  // XCD-aware bijective swizzle: 1024 blocks % 8 XCDs == 0
  const int bid = blockIdx.x;
  const int wg = (bid & 7) * 128 + (bid >> 3);
  const int m0 = (wg >> 4) * 128;  // 64 m-blocks
  const int n0 = (wg & 15) * 128;  // 16 n-blocks

  f32x4 acc[4][4];
#pragma unroll
  for (int a = 0; a < 4; ++a)
#pragma unroll
    for (int b = 0; b < 4; ++b)
#pragma unroll
      for (int i = 0; i < 4; ++i) acc[a][b][i] = 0.f;

  // bf16 staging lane map: 16B = 8 shorts; GLD16 covers 8 rows of 64 shorts
  //   lane -> row lane>>3, col (lane&7)*8; LDS linear offset lane*8 shorts.
  // fp32 staging lane map: 16B = 4 floats; GLD16 covers 4 rows of 64 floats
  //   lane -> row lane>>4, col (lane&15)*4; LDS linear offset lane*4 floats.
  const unsigned short* gA16 =
      ABF16 ? (const unsigned short*)Av + (size_t)(m0 + wave * 32 + (lane >> 3)) * K_DIM +
                  (lane & 7) * 8
            : (const unsigned short*)0;
  const float* gA32 = ABF16 ? (const float*)0
                            : (const float*)Av + (size_t)(m0 + wave * 32 + (lane >> 4)) * K_DIM +
                                  (lane & 15) * 4;
  const unsigned short* gB =
      Wt + (size_t)(n0 + wave * 32 + (lane >> 3)) * K_DIM + (lane & 7) * 8;

  for (int k0 = 0; k0 < K_DIM; k0 += 64) {
    __syncthreads();  // previous iteration's ds_reads done before overwrite
    if constexpr (ABF16) {
#pragma unroll
      for (int r = 0; r < 4; ++r) {
        GLD16(gA16 + (size_t)(r * 8) * K_DIM + k0, lsA + wave * 2048 + r * 512);
        GLD16(gB + (size_t)(r * 8) * K_DIM + k0, lsB + wave * 2048 + r * 512);
      }
    } else {
#pragma unroll
      for (int r = 0; r < 8; ++r)
        GLD16(gA32 + (size_t)(r * 4) * K_DIM + k0, lsAf + wave * 2048 + r * 256);
#pragma unroll
      for (int r = 0; r < 4; ++r)
        GLD16(gB + (size_t)(r * 8) * K_DIM + k0, lsB + wave * 2048 + r * 512);
    }
    __syncthreads();  // compiler drains vmcnt(0) before barrier: tiles ready

#pragma unroll
    for (int kk = 0; kk < 2; ++kk) {
      bf16x8 af[4], bfr[4];
#pragma unroll
      for (int mf = 0; mf < 4; ++mf) {
        if constexpr (ABF16) {
          af[mf] = *(const bf16x8*)(const void*)(lsA + (wm * 64 + mf * 16 + l16) * 64 + kk * 32 +
                                                 quad * 8);
        } else {
          const float* ap = lsAf + (wm * 64 + mf * 16 + l16) * 64 + kk * 32 + quad * 8;
          f32x4 a0 = *(const f32x4*)ap;
          f32x4 a1 = *(const f32x4*)(ap + 4);
#pragma unroll
          for (int j = 0; j < 4; ++j) {
            af[mf][j] = (__bf16)a0[j];
            af[mf][4 + j] = (__bf16)a1[j];
          }
        }
      }
#pragma unroll
      for (int nf = 0; nf < 4; ++nf)
        bfr[nf] = *(const bf16x8*)(const void*)(lsB + (wn * 64 + nf * 16 + l16) * 64 + kk * 32 +
                                                quad * 8);
#pragma unroll
      for (int mf = 0; mf < 4; ++mf)
#pragma unroll
        for (int nf = 0; nf < 4; ++nf)
          acc[mf][nf] =
              __builtin_amdgcn_mfma_f32_16x16x32_bf16(af[mf], bfr[nf], acc[mf][nf], 0, 0, 0);
    }
  }
  __syncthreads();  // all waves done with lsA/lsB before smem is reused as lsO

  // ---- epilogue (all fp32); C/D layout: col = l16 (n), row = quad*4 + r (m) ----
  const int c_base = n0 + wn * 64;  // wave's 64 columns == one GroupNorm group
  const int t_base = (m0 & (T_DIM - 1)) + wm * 64;

  float hb[4], gw[4], gb[4];
#pragma unroll
  for (int nf = 0; nf < 4; ++nf) {
    int c = c_base + nf * 16 + l16;
    hb[nf] = hhb[c];
    gw[nf] = gnw[c];
    gb[nf] = gnb[c];
  }

  // rope on channels 0..63 (exactly the c_base==0 wave); pair partner is lane^1
  if (c_base == 0) {
#pragma unroll
    for (int nf = 0; nf < 4; ++nf) {
      int c = nf * 16 + l16;
      int ii = c >> 1;
      float freq = expf(-(float)ii * 0.28782313662425572f);  // 10000^(-ii/32)
      float sgn = (c & 1) ? 1.f : -1.f;
#pragma unroll
      for (int mf = 0; mf < 4; ++mf)
#pragma unroll
        for (int r = 0; r < 4; ++r) {
          float v = acc[mf][nf][r];
          float p = __shfl_xor(v, 1, 64);
          int t = t_base + mf * 16 + quad * 4 + r;
          float ang = (float)t * freq;
          float s = sinf(ang);
          float co = cosf(ang);
          acc[mf][nf][r] = v * co + sgn * p * s;
        }
    }
  }

  // relu -> +bias -> tanh -> GroupNorm (64-ch group == this wave's columns)
#pragma unroll
  for (int mf = 0; mf < 4; ++mf)
#pragma unroll
    for (int r = 0; r < 4; ++r) {
      float h[4];
      float s1 = 0.f, s2 = 0.f;
#pragma unroll
      for (int nf = 0; nf < 4; ++nf) {
        float v = fmaxf(acc[mf][nf][r], 0.f) + hb[nf];
        float th = tanhf(v);
        h[nf] = th;
        s1 += th;
        s2 += th * th;
      }
      // butterfly over l16 bits (quad preserved): sums the 16 lanes x 4 nf = 64 ch
#pragma unroll
      for (int d = 1; d < 16; d <<= 1) {
        s1 += __shfl_xor(s1, d, 64);
        s2 += __shfl_xor(s2, d, 64);
      }
      float mu = s1 * 0.015625f;
      float var = s2 * 0.015625f - mu * mu;
      float rstd = rsqrtf(var + 1e-5f);
#pragma unroll
      for (int nf = 0; nf < 4; ++nf)
        acc[mf][nf][r] = (h[nf] - mu) * rstd * gw[nf] + gb[nf];  // y in place
    }

  // ---- transposed store via LDS, two 64-row chunks (wm==h waves own chunk h) ----
  const int bb = m0 >> 12;          // batch
  const int t0 = m0 & (T_DIM - 1);  // t of block row 0
#pragma unroll
  for (int h = 0; h < 2; ++h) {
    if (wm == h) {
#pragma unroll
      for (int mf = 0; mf < 4; ++mf)
#pragma unroll
        for (int r = 0; r < 4; ++r) {
          int t_in = mf * 16 + quad * 4 + r;
#pragma unroll
          for (int nf = 0; nf < 4; ++nf)
            lsO[wn * 64 + nf * 16 + l16][t_in] = acc[mf][nf][r];
        }
    }
    __syncthreads();
    // 128 c x 64 t floats = 2048 float4 slots; each thread 8
#pragma unroll
    for (int i = 0; i < 8; ++i) {
      int s = tid + i * 256;
      int cl = s >> 4;
      int t4 = (s & 15) * 4;
      float4 v = *(const float4*)&lsO[cl][t4];
      *(float4*)&out[(size_t)bb * C_DIM * T_DIM + (size_t)(n0 + cl) * T_DIM + t0 + h * 64 + t4] = v;
    }
    __syncthreads();  // before next chunk overwrites lsO
  }
}

// ---------------- S_n passthrough: (2,2048) fp32 after the big tensor ----------------
__global__ __launch_bounds__(256) void copy_sn(const float* __restrict__ src,
                                               float* __restrict__ dst) {
  int i = blockIdx.x * 256 + threadIdx.x;  // 0..4095
  dst[i] = src[i];
}

extern "C" void kernel_launch(void* const* d_in, const int* in_sizes, int n_in,
                              void* d_out, int out_size, void* d_ws, size_t ws_size,
                              hipStream_t stream) {
  const float* X = (const float*)d_in[0];
  const float* Sn = (const float*)d_in[1];
  const float* W = (const float*)d_in[2];
  const float* hhb = (const float*)d_in[3];
  const float* gnw = (const float*)d_in[4];
  const float* gnb = (const float*)d_in[5];
  float* out = (float*)d_out;

  // workspace layout: Wt bf16 [2048][2048] = 8 MB (always);
  // optional Xb bf16 [8192][2048] = 33.5 MB iff workspace is big enough.
  unsigned short* Wt = (unsigned short*)d_ws;
  const size_t wt_bytes = (size_t)C_DIM * K_DIM * 2;            // 8 MB
  const size_t xb_bytes = (size_t)2 * T_DIM * K_DIM * 2;        // 33.5 MB

  transpose_w<<<dim3(32, 32), dim3(256), 0, stream>>>(W, Wt);

  if (ws_size >= wt_bytes + xb_bytes) {
    unsigned short* Xb = Wt + (size_t)C_DIM * K_DIM;
    cvt_x<<<dim3(8192), dim3(256), 0, stream>>>(X, Xb);
    gemm_fused<true><<<dim3(1024), dim3(256), 0, stream>>>(Xb, Wt, hhb, gnw, gnb, out);
  } else {
    gemm_fused<false><<<dim3(1024), dim3(256), 0, stream>>>(X, Wt, hhb, gnw, gnb, out);
  }

  copy_sn<<<dim3(16), dim3(256), 0, stream>>>(Sn, out + (size_t)16777216);
}

// Round 3
// 344.733 us; speedup vs baseline: 4.5077x; 2.4844x over previous
//
#include <hip/hip_runtime.h>

#define T_DIM 4096
#define C_DIM 2048
#define K_DIM 2048

typedef __bf16 bf16x8 __attribute__((ext_vector_type(8)));
typedef float f32x4 __attribute__((ext_vector_type(4)));

__device__ __forceinline__ unsigned short f2bf(float f) {
  union { float f; unsigned int i; } x;
  x.f = f;
  unsigned int r = x.i + 0x7fffu + ((x.i >> 16) & 1u);  // round-to-nearest-even
  return (unsigned short)(r >> 16);
}

// async global->LDS, 16B per lane; LDS dest = wave-uniform base + lane*16
#define GLD16(gsrc, ldst)                                                   \
  __builtin_amdgcn_global_load_lds(                                         \
      (const __attribute__((address_space(1))) unsigned int*)(gsrc),        \
      (__attribute__((address_space(3))) unsigned int*)(ldst), 16, 0, 0)

// ---------------- W (K x N) fp32 -> Wt (N x K) bf16 ----------------
__global__ __launch_bounds__(256) void transpose_w(const float* __restrict__ W,
                                                   unsigned short* __restrict__ Wt) {
  __shared__ float tile[64][68];  // +4 pad
  const int c0 = blockIdx.x * 64;  // n
  const int r0 = blockIdx.y * 64;  // k
  const int tid = threadIdx.x;
#pragma unroll
  for (int i = 0; i < 4; ++i) {
    int s = tid + i * 256;  // 0..1023 float4 slots (64 rows x 16 slots)
    int r = s >> 4, c4 = (s & 15) * 4;
    *(float4*)&tile[r][c4] = *(const float4*)&W[(size_t)(r0 + r) * C_DIM + c0 + c4];
  }
  __syncthreads();
#pragma unroll
  for (int i = 0; i < 2; ++i) {
    int s = tid + i * 256;  // 0..511: 64 n-rows x 8 slots of 8 bf16
    int n = s >> 3, k8 = (s & 7) * 8;
    __align__(16) unsigned short tmp[8];
#pragma unroll
    for (int j = 0; j < 8; ++j) tmp[j] = f2bf(tile[k8 + j][n]);
    *(uint4*)&Wt[(size_t)(c0 + n) * K_DIM + r0 + k8] = *(uint4*)tmp;
  }
}

// ---------------- X fp32 -> Xb bf16 (one pass, RNE identical to f2bf staging) ----------------
__global__ __launch_bounds__(256) void cvt_x(const float* __restrict__ X,
                                             unsigned short* __restrict__ Xb) {
  size_t base = (size_t)blockIdx.x * 2048 + (size_t)threadIdx.x * 8;
  float4 a = *(const float4*)&X[base];
  float4 b = *(const float4*)&X[base + 4];
  __align__(16) unsigned short t[8];
  t[0] = f2bf(a.x); t[1] = f2bf(a.y); t[2] = f2bf(a.z); t[3] = f2bf(a.w);
  t[4] = f2bf(b.x); t[5] = f2bf(b.y); t[6] = f2bf(b.z); t[7] = f2bf(b.w);
  *(uint4*)&Xb[base] = *(const uint4*)t;
}

// -------- macro helpers: named accumulators (forces SROA -> registers) --------
#define FOR_MN(OP) \
  OP(0,0) OP(0,1) OP(0,2) OP(0,3) \
  OP(1,0) OP(1,1) OP(1,2) OP(1,3) \
  OP(2,0) OP(2,1) OP(2,2) OP(2,3) \
  OP(3,0) OP(3,1) OP(3,2) OP(3,3)

#define DECL_ACC(m,n) f32x4 a##m##n = {0.f, 0.f, 0.f, 0.f};

// ------- fused GEMM + rope + relu + bias + tanh + GroupNorm + transpose -------
// B (Wt) bf16 [n][k] staged via global_load_lds with XOR-swizzled source col
// (col_shorts ^= (row&7)<<3) so ds_read_b128 frag reads are ~2-way (free) instead
// of 16-way bank-conflicted; same XOR applied on the read side (rule #21).
// A: bf16 Xb (fast path, swizzled like B) or fp32 X fallback (linear, cvt at read).
template <bool ABF16>
__global__ __launch_bounds__(256, 3) void gemm_fused(const void* __restrict__ Av,
                                                     const unsigned short* __restrict__ Wt,
                                                     const float* __restrict__ hhb,
                                                     const float* __restrict__ gnw,
                                                     const float* __restrict__ gnb,
                                                     float* __restrict__ out) {
  constexpr int SMEM_BYTES = ABF16 ? 34816 : 49152;
  __shared__ __align__(16) char smem[SMEM_BYTES];
  unsigned short* lsA = (unsigned short*)smem;                    // bf16 path: [128][64] 16KB
  float* lsAf = (float*)smem;                                     // fp32 path: [128][64] 32KB
  unsigned short* lsB = (unsigned short*)(smem + (ABF16 ? 16384 : 32768));  // 16KB
  float(*lsO)[68] = (float(*)[68])smem;                           // epilogue reuse, 34.8KB

  const int tid = threadIdx.x;
  const int wave = tid >> 6;
  const int lane = tid & 63;
  const int quad = lane >> 4;
  const int l16 = lane & 15;
  const int wm = wave >> 1, wn = wave & 1;

  // XCD-aware bijective swizzle: 1024 blocks % 8 XCDs == 0
  const int bid = blockIdx.x;
  const int wg = (bid & 7) * 128 + (bid >> 3);
  const int m0 = (wg >> 4) * 128;  // 64 m-blocks
  const int n0 = (wg & 15) * 128;  // 16 n-blocks

  FOR_MN(DECL_ACC)

  // staging lane map (bf16, 16B=8 shorts): row = lane>>3, swizzled col
  const int srow = lane >> 3;
  const int scol = ((lane & 7) * 8) ^ ((srow & 7) << 3);  // XOR-pre-swizzled source col
  const unsigned short* gA16 =
      ABF16 ? (const unsigned short*)Av + (size_t)(m0 + wave * 32 + srow) * K_DIM + scol
            : (const unsigned short*)0;
  // fp32 fallback staging (linear): row = lane>>4, col = (lane&15)*4 floats
  const float* gA32 = ABF16 ? (const float*)0
                            : (const float*)Av + (size_t)(m0 + wave * 32 + (lane >> 4)) * K_DIM +
                                  (lane & 15) * 4;
  const unsigned short* gB = Wt + (size_t)(n0 + wave * 32 + srow) * K_DIM + scol;

  for (int k0 = 0; k0 < K_DIM; k0 += 64) {
    __syncthreads();  // previous iteration's ds_reads done before overwrite
    if constexpr (ABF16) {
#pragma unroll
      for (int r = 0; r < 4; ++r) {
        GLD16(gA16 + (size_t)(r * 8) * K_DIM + k0, lsA + wave * 2048 + r * 512);
        GLD16(gB + (size_t)(r * 8) * K_DIM + k0, lsB + wave * 2048 + r * 512);
      }
    } else {
#pragma unroll
      for (int r = 0; r < 8; ++r)
        GLD16(gA32 + (size_t)(r * 4) * K_DIM + k0, lsAf + wave * 2048 + r * 256);
#pragma unroll
      for (int r = 0; r < 4; ++r)
        GLD16(gB + (size_t)(r * 8) * K_DIM + k0, lsB + wave * 2048 + r * 512);
    }
    __syncthreads();  // vmcnt(0) drained before barrier: tiles ready

#pragma unroll
    for (int kk = 0; kk < 2; ++kk) {
      const int xs = (kk * 32 + quad * 8) ^ ((l16 & 7) << 3);  // swizzled read offset (shorts)

#define LOAD_AF(m)                                                                   \
      bf16x8 af##m;                                                                  \
      if constexpr (ABF16) {                                                         \
        af##m = *(const bf16x8*)(const void*)(lsA + (wm * 64 + m * 16 + l16) * 64 + xs); \
      } else {                                                                       \
        const float* ap_ = lsAf + (wm * 64 + m * 16 + l16) * 64 + kk * 32 + quad * 8; \
        f32x4 a0_ = *(const f32x4*)ap_;                                              \
        f32x4 a1_ = *(const f32x4*)(ap_ + 4);                                        \
        af##m[0] = (__bf16)a0_[0]; af##m[1] = (__bf16)a0_[1];                        \
        af##m[2] = (__bf16)a0_[2]; af##m[3] = (__bf16)a0_[3];                        \
        af##m[4] = (__bf16)a1_[0]; af##m[5] = (__bf16)a1_[1];                        \
        af##m[6] = (__bf16)a1_[2]; af##m[7] = (__bf16)a1_[3];                        \
      }
#define LOAD_BF(n)                                                                   \
      bf16x8 bfr##n = *(const bf16x8*)(const void*)(lsB + (wn * 64 + n * 16 + l16) * 64 + xs);

      LOAD_AF(0) LOAD_AF(1) LOAD_AF(2) LOAD_AF(3)
      LOAD_BF(0) LOAD_BF(1) LOAD_BF(2) LOAD_BF(3)

#define MFMA_OP(m,n) \
      a##m##n = __builtin_amdgcn_mfma_f32_16x16x32_bf16(af##m, bfr##n, a##m##n, 0, 0, 0);
      FOR_MN(MFMA_OP)
#undef LOAD_AF
#undef LOAD_BF
    }
  }
  __syncthreads();  // all waves done with lsA/lsB before smem is reused as lsO

  // ---- epilogue (all fp32); C/D layout: col = l16 (n), row = quad*4 + r (m) ----
  const int c_base = n0 + wn * 64;  // wave's 64 columns == one GroupNorm group
  const int t_base = (m0 & (T_DIM - 1)) + wm * 64;

#define LOADC(n)                                  \
  const int c##n = c_base + n * 16 + l16;         \
  const float hb##n = hhb[c##n];                  \
  const float gw##n = gnw[c##n];                  \
  const float gb##n = gnb[c##n];
  LOADC(0) LOADC(1) LOADC(2) LOADC(3)

  // rope on channels 0..63 (exactly the c_base==0 wave); pair partner is lane^1
  if (c_base == 0) {
#define ROPE_E(n,m,r)                                                   \
    { float v_ = a##m##n[r];                                            \
      float p_ = __shfl_xor(v_, 1, 64);                                 \
      int t_ = t_base + m * 16 + quad * 4 + r;                          \
      float ang_ = (float)t_ * fr_;                                     \
      float s_ = sinf(ang_);                                            \
      float co_ = cosf(ang_);                                           \
      a##m##n[r] = v_ * co_ + sg_ * p_ * s_; }
#define ROPE_M(n,m) ROPE_E(n,m,0) ROPE_E(n,m,1) ROPE_E(n,m,2) ROPE_E(n,m,3)
#define ROPE_N(n)                                                       \
    { int cc_ = n * 16 + l16;                                           \
      int ii_ = cc_ >> 1;                                               \
      float fr_ = expf(-(float)ii_ * 0.28782313662425572f);             \
      float sg_ = (cc_ & 1) ? 1.f : -1.f;                               \
      ROPE_M(n,0) ROPE_M(n,1) ROPE_M(n,2) ROPE_M(n,3) }
    ROPE_N(0) ROPE_N(1) ROPE_N(2) ROPE_N(3)
  }

  // relu -> +bias -> tanh -> GroupNorm (64-ch group == this wave's columns)
#define GN_ROW(m,r)                                                     \
  { float h0_ = tanhf(fmaxf(a##m##0[r], 0.f) + hb0);                    \
    float h1_ = tanhf(fmaxf(a##m##1[r], 0.f) + hb1);                    \
    float h2_ = tanhf(fmaxf(a##m##2[r], 0.f) + hb2);                    \
    float h3_ = tanhf(fmaxf(a##m##3[r], 0.f) + hb3);                    \
    float s1_ = h0_ + h1_ + h2_ + h3_;                                  \
    float s2_ = h0_ * h0_ + h1_ * h1_ + h2_ * h2_ + h3_ * h3_;          \
    s1_ += __shfl_xor(s1_, 1, 64);  s2_ += __shfl_xor(s2_, 1, 64);      \
    s1_ += __shfl_xor(s1_, 2, 64);  s2_ += __shfl_xor(s2_, 2, 64);      \
    s1_ += __shfl_xor(s1_, 4, 64);  s2_ += __shfl_xor(s2_, 4, 64);      \
    s1_ += __shfl_xor(s1_, 8, 64);  s2_ += __shfl_xor(s2_, 8, 64);      \
    float mu_ = s1_ * 0.015625f;                                        \
    float var_ = s2_ * 0.015625f - mu_ * mu_;                           \
    float rs_ = rsqrtf(var_ + 1e-5f);                                   \
    a##m##0[r] = (h0_ - mu_) * rs_ * gw0 + gb0;                         \
    a##m##1[r] = (h1_ - mu_) * rs_ * gw1 + gb1;                         \
    a##m##2[r] = (h2_ - mu_) * rs_ * gw2 + gb2;                         \
    a##m##3[r] = (h3_ - mu_) * rs_ * gw3 + gb3; }
#define GN_M(m) GN_ROW(m,0) GN_ROW(m,1) GN_ROW(m,2) GN_ROW(m,3)
  GN_M(0) GN_M(1) GN_M(2) GN_M(3)

  // ---- transposed store via LDS, two 64-row chunks (wm==h waves own chunk h) ----
  const int bb = m0 >> 12;          // batch
  const int t0 = m0 & (T_DIM - 1);  // t of block row 0
#define ST_MN(m,n)                                                      \
  lsO[wn * 64 + n * 16 + l16][m * 16 + quad * 4 + 0] = a##m##n[0];      \
  lsO[wn * 64 + n * 16 + l16][m * 16 + quad * 4 + 1] = a##m##n[1];      \
  lsO[wn * 64 + n * 16 + l16][m * 16 + quad * 4 + 2] = a##m##n[2];      \
  lsO[wn * 64 + n * 16 + l16][m * 16 + quad * 4 + 3] = a##m##n[3];
#pragma unroll
  for (int h = 0; h < 2; ++h) {
    if (wm == h) {
      FOR_MN(ST_MN)
    }
    __syncthreads();
    // 128 c x 64 t floats = 2048 float4 slots; each thread 8
#pragma unroll
    for (int i = 0; i < 8; ++i) {
      int s = tid + i * 256;
      int cl = s >> 4;
      int t4 = (s & 15) * 4;
      float4 v = *(const float4*)&lsO[cl][t4];
      *(float4*)&out[(size_t)bb * C_DIM * T_DIM + (size_t)(n0 + cl) * T_DIM + t0 + h * 64 + t4] = v;
    }
    __syncthreads();  // before next chunk overwrites lsO
  }
}

// ---------------- S_n passthrough: (2,2048) fp32 after the big tensor ----------------
__global__ __launch_bounds__(256) void copy_sn(const float* __restrict__ src,
                                               float* __restrict__ dst) {
  int i = blockIdx.x * 256 + threadIdx.x;  // 0..4095
  dst[i] = src[i];
}

extern "C" void kernel_launch(void* const* d_in, const int* in_sizes, int n_in,
                              void* d_out, int out_size, void* d_ws, size_t ws_size,
                              hipStream_t stream) {
  const float* X = (const float*)d_in[0];
  const float* Sn = (const float*)d_in[1];
  const float* W = (const float*)d_in[2];
  const float* hhb = (const float*)d_in[3];
  const float* gnw = (const float*)d_in[4];
  const float* gnb = (const float*)d_in[5];
  float* out = (float*)d_out;

  // workspace layout: Wt bf16 [2048][2048] = 8 MB (always);
  // optional Xb bf16 [8192][2048] = 33.5 MB iff workspace is big enough.
  unsigned short* Wt = (unsigned short*)d_ws;
  const size_t wt_bytes = (size_t)C_DIM * K_DIM * 2;      // 8 MB
  const size_t xb_bytes = (size_t)2 * T_DIM * K_DIM * 2;  // 33.5 MB

  transpose_w<<<dim3(32, 32), dim3(256), 0, stream>>>(W, Wt);

  if (ws_size >= wt_bytes + xb_bytes) {
    unsigned short* Xb = Wt + (size_t)C_DIM * K_DIM;
    cvt_x<<<dim3(8192), dim3(256), 0, stream>>>(X, Xb);
    gemm_fused<true><<<dim3(1024), dim3(256), 0, stream>>>(Xb, Wt, hhb, gnw, gnb, out);
  } else {
    gemm_fused<false><<<dim3(1024), dim3(256), 0, stream>>>(X, Wt, hhb, gnw, gnb, out);
  }

  copy_sn<<<dim3(16), dim3(256), 0, stream>>>(Sn, out + (size_t)16777216);
}

// Round 4
// 342.628 us; speedup vs baseline: 4.5354x; 1.0061x over previous
//
#include <hip/hip_runtime.h>

#define T_DIM 4096
#define C_DIM 2048
#define K_DIM 2048

typedef __bf16 bf16x8 __attribute__((ext_vector_type(8)));
typedef float f32x4 __attribute__((ext_vector_type(4)));

__device__ __forceinline__ unsigned short f2bf(float f) {
  union { float f; unsigned int i; } x;
  x.f = f;
  unsigned int r = x.i + 0x7fffu + ((x.i >> 16) & 1u);  // round-to-nearest-even
  return (unsigned short)(r >> 16);
}

// async global->LDS, 16B per lane; LDS dest = wave-uniform base + lane*16
#define GLD16(gsrc, ldst)                                                   \
  __builtin_amdgcn_global_load_lds(                                         \
      (const __attribute__((address_space(1))) unsigned int*)(gsrc),        \
      (__attribute__((address_space(3))) unsigned int*)(ldst), 16, 0, 0)

// ---------------- W (K x N) fp32 -> Wt (N x K) bf16 ----------------
__global__ __launch_bounds__(256) void transpose_w(const float* __restrict__ W,
                                                   unsigned short* __restrict__ Wt) {
  __shared__ float tile[64][68];  // +4 pad
  const int c0 = blockIdx.x * 64;  // n
  const int r0 = blockIdx.y * 64;  // k
  const int tid = threadIdx.x;
#pragma unroll
  for (int i = 0; i < 4; ++i) {
    int s = tid + i * 256;  // 0..1023 float4 slots (64 rows x 16 slots)
    int r = s >> 4, c4 = (s & 15) * 4;
    *(float4*)&tile[r][c4] = *(const float4*)&W[(size_t)(r0 + r) * C_DIM + c0 + c4];
  }
  __syncthreads();
#pragma unroll
  for (int i = 0; i < 2; ++i) {
    int s = tid + i * 256;  // 0..511: 64 n-rows x 8 slots of 8 bf16
    int n = s >> 3, k8 = (s & 7) * 8;
    __align__(16) unsigned short tmp[8];
#pragma unroll
    for (int j = 0; j < 8; ++j) tmp[j] = f2bf(tile[k8 + j][n]);
    *(uint4*)&Wt[(size_t)(c0 + n) * K_DIM + r0 + k8] = *(uint4*)tmp;
  }
}

// ---------------- X fp32 -> Xb bf16 (one pass, RNE identical to f2bf staging) ----------------
__global__ __launch_bounds__(256) void cvt_x(const float* __restrict__ X,
                                             unsigned short* __restrict__ Xb) {
  size_t base = (size_t)blockIdx.x * 2048 + (size_t)threadIdx.x * 8;
  float4 a = *(const float4*)&X[base];
  float4 b = *(const float4*)&X[base + 4];
  __align__(16) unsigned short t[8];
  t[0] = f2bf(a.x); t[1] = f2bf(a.y); t[2] = f2bf(a.z); t[3] = f2bf(a.w);
  t[4] = f2bf(b.x); t[5] = f2bf(b.y); t[6] = f2bf(b.z); t[7] = f2bf(b.w);
  *(uint4*)&Xb[base] = *(const uint4*)t;
}

// -------- macro helpers: named accumulators (forces SROA -> registers) --------
#define FOR_MN(OP) \
  OP(0,0) OP(0,1) OP(0,2) OP(0,3) \
  OP(1,0) OP(1,1) OP(1,2) OP(1,3) \
  OP(2,0) OP(2,1) OP(2,2) OP(2,3) \
  OP(3,0) OP(3,1) OP(3,2) OP(3,3)

#define DECL_ACC(m,n) f32x4 a##m##n = {0.f, 0.f, 0.f, 0.f};

// ------- fused GEMM + rope + relu + bias + tanh + GroupNorm + transpose -------
// T3-minimum pipeline: BK=32, double-buffered LDS tiles, counted vmcnt, raw
// barriers (no compiler vmcnt(0) drain). Bank swizzle on 8-short units:
// col8 ^= (row&3) for bf16 64B rows; (row&7) for fp32 128B rows. Swizzle is an
// involution applied on BOTH the global staging source and the ds_read address.
template <bool ABF16>
__global__ __launch_bounds__(256, 3) void gemm_fused(const void* __restrict__ Av,
                                                     const unsigned short* __restrict__ Wt,
                                                     const float* __restrict__ hhb,
                                                     const float* __restrict__ gnw,
                                                     const float* __restrict__ gnb,
                                                     float* __restrict__ out) {
  // bf16: A bufs 2x4096 shorts @0, B bufs 2x4096 shorts @16384; union lsO 34816.
  // fp32: Af bufs 2x4096 floats @0, B bufs 2x4096 shorts @32768; union 49152.
  constexpr int SMEM_BYTES = ABF16 ? 34816 : 49152;
  __shared__ __align__(16) char smem[SMEM_BYTES];
  unsigned short* lsA = (unsigned short*)smem;
  float* lsAf = (float*)smem;
  unsigned short* lsB = (unsigned short*)(smem + (ABF16 ? 16384 : 32768));
  float(*lsO)[68] = (float(*)[68])smem;  // epilogue reuse

  const int tid = threadIdx.x;
  const int wave = tid >> 6;
  const int lane = tid & 63;
  const int quad = lane >> 4;
  const int l16 = lane & 15;
  const int wm = wave >> 1, wn = wave & 1;

  // XCD-aware bijective swizzle: 1024 blocks % 8 XCDs == 0
  const int bid = blockIdx.x;
  const int wg = (bid & 7) * 128 + (bid >> 3);
  const int m0 = (wg >> 4) * 128;  // 64 m-blocks
  const int n0 = (wg & 15) * 128;  // 16 n-blocks

  FOR_MN(DECL_ACC)

  // ---- staging lane maps (per GLD16: 64 lanes x 16B = 1KB) ----
  // bf16 tile [128][32] shorts (64B rows): GLD16 covers 16 rows.
  //   lane -> row lane>>2, col8 = (lane&3); source col8 ^= (row&3).
  const int srow16 = lane >> 2;
  const int scol16 = (((lane & 3) ^ (srow16 & 3)) * 8);
  // fp32 tile [128][32] floats (128B rows): GLD16 covers 8 rows.
  //   lane -> row lane>>3, unit16B = lane&7; source unit ^= (row&7).
  const int srow32 = lane >> 3;
  const int scol32 = (((lane & 7) ^ srow32) * 4);

  const unsigned short* gA16 =
      ABF16 ? (const unsigned short*)Av + (size_t)(m0 + wave * 32 + srow16) * K_DIM + scol16
            : (const unsigned short*)0;
  const float* gA32 =
      ABF16 ? (const float*)0
            : (const float*)Av + (size_t)(m0 + wave * 32 + srow32) * K_DIM + scol32;
  const unsigned short* gB16 =
      Wt + (size_t)(n0 + wave * 32 + srow16) * K_DIM + scol16;

  // ---- fragment read addresses (swizzled, cur-buffer relative) ----
  const int axs = (quad ^ (l16 & 3)) * 8;                 // bf16 read col (shorts)
  const int abase = (wm * 64 + l16) * 32 + axs;           // + m*512
  const int bbase = (wn * 64 + l16) * 32 + axs;           // + n*512
  const int abasef = (wm * 64 + l16) * 32;                // fp32 (floats), + m*512
  const int u0 = ((2 * quad) ^ (l16 & 7)) * 4;            // fp32 16B-unit offsets
  const int u1 = ((2 * quad + 1) ^ (l16 & 7)) * 4;

  auto stage = [&](int d, int koff) {
    if constexpr (ABF16) {
      GLD16(gA16 + koff, lsA + d * 4096 + wave * 1024);
      GLD16(gA16 + koff + 16 * K_DIM, lsA + d * 4096 + wave * 1024 + 512);
    } else {
      GLD16(gA32 + koff, lsAf + d * 4096 + wave * 1024);
      GLD16(gA32 + koff + 8 * K_DIM, lsAf + d * 4096 + wave * 1024 + 256);
      GLD16(gA32 + koff + 16 * K_DIM, lsAf + d * 4096 + wave * 1024 + 512);
      GLD16(gA32 + koff + 24 * K_DIM, lsAf + d * 4096 + wave * 1024 + 768);
    }
    GLD16(gB16 + koff, lsB + d * 4096 + wave * 1024);
    GLD16(gB16 + koff + 16 * K_DIM, lsB + d * 4096 + wave * 1024 + 512);
  };

  constexpr int NT = K_DIM / 32;  // 64 K-tiles

  stage(0, 0);  // prologue: tile 0 in flight
  for (int t = 0; t < NT; ++t) {
    const int cur = t & 1;
    if (t + 1 < NT) {
      stage(cur ^ 1, (t + 1) * 32);  // next tile async into other buffer
      // wait tile t only: the (4|6) just-issued loads stay in flight
      if constexpr (ABF16)
        asm volatile("s_waitcnt vmcnt(4)" ::: "memory");
      else
        asm volatile("s_waitcnt vmcnt(6)" ::: "memory");
    } else {
      asm volatile("s_waitcnt vmcnt(0)" ::: "memory");
    }
    __builtin_amdgcn_s_barrier();  // raw: no vmcnt(0) drain of in-flight prefetch
    asm volatile("" ::: "memory");

    const unsigned short* pa = lsA + cur * 4096;
    const float* paf = lsAf + cur * 4096;
    const unsigned short* pb = lsB + cur * 4096;

#define LOAD_AF(m)                                                        \
    bf16x8 af##m;                                                         \
    if constexpr (ABF16) {                                                \
      af##m = *(const bf16x8*)(const void*)(pa + abase + m * 512);        \
    } else {                                                              \
      const float* ap_ = paf + abasef + m * 512;                          \
      f32x4 a0_ = *(const f32x4*)(ap_ + u0);                              \
      f32x4 a1_ = *(const f32x4*)(ap_ + u1);                              \
      af##m[0] = (__bf16)a0_[0]; af##m[1] = (__bf16)a0_[1];               \
      af##m[2] = (__bf16)a0_[2]; af##m[3] = (__bf16)a0_[3];               \
      af##m[4] = (__bf16)a1_[0]; af##m[5] = (__bf16)a1_[1];               \
      af##m[6] = (__bf16)a1_[2]; af##m[7] = (__bf16)a1_[3];               \
    }
#define LOAD_BF(n)                                                        \
    bf16x8 bfr##n = *(const bf16x8*)(const void*)(pb + bbase + n * 512);

    LOAD_AF(0) LOAD_AF(1) LOAD_AF(2) LOAD_AF(3)
    LOAD_BF(0) LOAD_BF(1) LOAD_BF(2) LOAD_BF(3)

#define MFMA_OP(m,n) \
    a##m##n = __builtin_amdgcn_mfma_f32_16x16x32_bf16(af##m, bfr##n, a##m##n, 0, 0, 0);
    FOR_MN(MFMA_OP)
#undef LOAD_AF
#undef LOAD_BF

    // all ds_reads of buf[cur] retired before it is re-staged at t+1's top
    asm volatile("s_waitcnt lgkmcnt(0)" ::: "memory");
    __builtin_amdgcn_sched_barrier(0);
    __builtin_amdgcn_s_barrier();
    asm volatile("" ::: "memory");
  }

  // ---- epilogue (all fp32); C/D layout: col = l16 (n), row = quad*4 + r (m) ----
  const int c_base = n0 + wn * 64;  // wave's 64 columns == one GroupNorm group
  const int t_base = (m0 & (T_DIM - 1)) + wm * 64;

#define LOADC(n)                                  \
  const int c##n = c_base + n * 16 + l16;         \
  const float hb##n = hhb[c##n];                  \
  const float gw##n = gnw[c##n];                  \
  const float gb##n = gnb[c##n];
  LOADC(0) LOADC(1) LOADC(2) LOADC(3)

  // rope on channels 0..63 (exactly the c_base==0 wave); pair partner is lane^1
  if (c_base == 0) {
#define ROPE_E(n,m,r)                                                   \
    { float v_ = a##m##n[r];                                            \
      float p_ = __shfl_xor(v_, 1, 64);                                 \
      int t_ = t_base + m * 16 + quad * 4 + r;                          \
      float ang_ = (float)t_ * fr_;                                     \
      float s_ = sinf(ang_);                                            \
      float co_ = cosf(ang_);                                           \
      a##m##n[r] = v_ * co_ + sg_ * p_ * s_; }
#define ROPE_M(n,m) ROPE_E(n,m,0) ROPE_E(n,m,1) ROPE_E(n,m,2) ROPE_E(n,m,3)
#define ROPE_N(n)                                                       \
    { int cc_ = n * 16 + l16;                                           \
      int ii_ = cc_ >> 1;                                               \
      float fr_ = expf(-(float)ii_ * 0.28782313662425572f);             \
      float sg_ = (cc_ & 1) ? 1.f : -1.f;                               \
      ROPE_M(n,0) ROPE_M(n,1) ROPE_M(n,2) ROPE_M(n,3) }
    ROPE_N(0) ROPE_N(1) ROPE_N(2) ROPE_N(3)
  }

  // relu -> +bias -> tanh -> GroupNorm (64-ch group == this wave's columns)
#define GN_ROW(m,r)                                                     \
  { float h0_ = tanhf(fmaxf(a##m##0[r], 0.f) + hb0);                    \
    float h1_ = tanhf(fmaxf(a##m##1[r], 0.f) + hb1);                    \
    float h2_ = tanhf(fmaxf(a##m##2[r], 0.f) + hb2);                    \
    float h3_ = tanhf(fmaxf(a##m##3[r], 0.f) + hb3);                    \
    float s1_ = h0_ + h1_ + h2_ + h3_;                                  \
    float s2_ = h0_ * h0_ + h1_ * h1_ + h2_ * h2_ + h3_ * h3_;          \
    s1_ += __shfl_xor(s1_, 1, 64);  s2_ += __shfl_xor(s2_, 1, 64);      \
    s1_ += __shfl_xor(s1_, 2, 64);  s2_ += __shfl_xor(s2_, 2, 64);      \
    s1_ += __shfl_xor(s1_, 4, 64);  s2_ += __shfl_xor(s2_, 4, 64);      \
    s1_ += __shfl_xor(s1_, 8, 64);  s2_ += __shfl_xor(s2_, 8, 64);      \
    float mu_ = s1_ * 0.015625f;                                        \
    float var_ = s2_ * 0.015625f - mu_ * mu_;                           \
    float rs_ = rsqrtf(var_ + 1e-5f);                                   \
    a##m##0[r] = (h0_ - mu_) * rs_ * gw0 + gb0;                         \
    a##m##1[r] = (h1_ - mu_) * rs_ * gw1 + gb1;                         \
    a##m##2[r] = (h2_ - mu_) * rs_ * gw2 + gb2;                         \
    a##m##3[r] = (h3_ - mu_) * rs_ * gw3 + gb3; }
#define GN_M(m) GN_ROW(m,0) GN_ROW(m,1) GN_ROW(m,2) GN_ROW(m,3)
  GN_M(0) GN_M(1) GN_M(2) GN_M(3)

  // ---- transposed store via LDS, two 64-row chunks (wm==h waves own chunk h) ----
  const int bb = m0 >> 12;          // batch
  const int t0 = m0 & (T_DIM - 1);  // t of block row 0
#define ST_MN(m,n)                                                      \
  lsO[wn * 64 + n * 16 + l16][m * 16 + quad * 4 + 0] = a##m##n[0];      \
  lsO[wn * 64 + n * 16 + l16][m * 16 + quad * 4 + 1] = a##m##n[1];      \
  lsO[wn * 64 + n * 16 + l16][m * 16 + quad * 4 + 2] = a##m##n[2];      \
  lsO[wn * 64 + n * 16 + l16][m * 16 + quad * 4 + 3] = a##m##n[3];
#pragma unroll
  for (int h = 0; h < 2; ++h) {
    if (wm == h) {
      FOR_MN(ST_MN)
    }
    __syncthreads();
    // 128 c x 64 t floats = 2048 float4 slots; each thread 8
#pragma unroll
    for (int i = 0; i < 8; ++i) {
      int s = tid + i * 256;
      int cl = s >> 4;
      int t4 = (s & 15) * 4;
      float4 v = *(const float4*)&lsO[cl][t4];
      *(float4*)&out[(size_t)bb * C_DIM * T_DIM + (size_t)(n0 + cl) * T_DIM + t0 + h * 64 + t4] = v;
    }
    __syncthreads();  // before next chunk overwrites lsO
  }
}

// ---------------- S_n passthrough: (2,2048) fp32 after the big tensor ----------------
__global__ __launch_bounds__(256) void copy_sn(const float* __restrict__ src,
                                               float* __restrict__ dst) {
  int i = blockIdx.x * 256 + threadIdx.x;  // 0..4095
  dst[i] = src[i];
}

extern "C" void kernel_launch(void* const* d_in, const int* in_sizes, int n_in,
                              void* d_out, int out_size, void* d_ws, size_t ws_size,
                              hipStream_t stream) {
  const float* X = (const float*)d_in[0];
  const float* Sn = (const float*)d_in[1];
  const float* W = (const float*)d_in[2];
  const float* hhb = (const float*)d_in[3];
  const float* gnw = (const float*)d_in[4];
  const float* gnb = (const float*)d_in[5];
  float* out = (float*)d_out;

  // workspace layout: Wt bf16 [2048][2048] = 8 MB (always);
  // optional Xb bf16 [8192][2048] = 33.5 MB iff workspace is big enough.
  unsigned short* Wt = (unsigned short*)d_ws;
  const size_t wt_bytes = (size_t)C_DIM * K_DIM * 2;      // 8 MB
  const size_t xb_bytes = (size_t)2 * T_DIM * K_DIM * 2;  // 33.5 MB

  transpose_w<<<dim3(32, 32), dim3(256), 0, stream>>>(W, Wt);

  if (ws_size >= wt_bytes + xb_bytes) {
    unsigned short* Xb = Wt + (size_t)C_DIM * K_DIM;
    cvt_x<<<dim3(8192), dim3(256), 0, stream>>>(X, Xb);
    gemm_fused<true><<<dim3(1024), dim3(256), 0, stream>>>(Xb, Wt, hhb, gnw, gnb, out);
  } else {
    gemm_fused<false><<<dim3(1024), dim3(256), 0, stream>>>(X, Wt, hhb, gnw, gnb, out);
  }

  copy_sn<<<dim3(16), dim3(256), 0, stream>>>(Sn, out + (size_t)16777216);
}

// Round 5
// 295.611 us; speedup vs baseline: 5.2567x; 1.1591x over previous
//
#include <hip/hip_runtime.h>

#define T_DIM 4096
#define C_DIM 2048
#define K_DIM 2048

typedef __bf16 bf16x8 __attribute__((ext_vector_type(8)));
typedef float f32x4 __attribute__((ext_vector_type(4)));

__device__ __forceinline__ unsigned short f2bf(float f) {
  union { float f; unsigned int i; } x;
  x.f = f;
  unsigned int r = x.i + 0x7fffu + ((x.i >> 16) & 1u);  // round-to-nearest-even
  return (unsigned short)(r >> 16);
}

// async global->LDS, 16B per lane; LDS dest = wave-uniform base + lane*16
#define GLD16(gsrc, ldst)                                                   \
  __builtin_amdgcn_global_load_lds(                                         \
      (const __attribute__((address_space(1))) unsigned int*)(gsrc),        \
      (__attribute__((address_space(3))) unsigned int*)(ldst), 16, 0, 0)

// ---------------- W (K x N) fp32 -> Wt (N x K) bf16 ----------------
__global__ __launch_bounds__(256) void transpose_w(const float* __restrict__ W,
                                                   unsigned short* __restrict__ Wt) {
  __shared__ float tile[64][68];  // +4 pad
  const int c0 = blockIdx.x * 64;  // n
  const int r0 = blockIdx.y * 64;  // k
  const int tid = threadIdx.x;
#pragma unroll
  for (int i = 0; i < 4; ++i) {
    int s = tid + i * 256;  // 0..1023 float4 slots (64 rows x 16 slots)
    int r = s >> 4, c4 = (s & 15) * 4;
    *(float4*)&tile[r][c4] = *(const float4*)&W[(size_t)(r0 + r) * C_DIM + c0 + c4];
  }
  __syncthreads();
#pragma unroll
  for (int i = 0; i < 2; ++i) {
    int s = tid + i * 256;  // 0..511: 64 n-rows x 8 slots of 8 bf16
    int n = s >> 3, k8 = (s & 7) * 8;
    __align__(16) unsigned short tmp[8];
#pragma unroll
    for (int j = 0; j < 8; ++j) tmp[j] = f2bf(tile[k8 + j][n]);
    *(uint4*)&Wt[(size_t)(c0 + n) * K_DIM + r0 + k8] = *(uint4*)tmp;
  }
}

// ---------------- X fp32 -> Xb bf16 (one pass, RNE identical to f2bf staging) ----------------
__global__ __launch_bounds__(256) void cvt_x(const float* __restrict__ X,
                                             unsigned short* __restrict__ Xb) {
  size_t base = (size_t)blockIdx.x * 2048 + (size_t)threadIdx.x * 8;
  float4 a = *(const float4*)&X[base];
  float4 b = *(const float4*)&X[base + 4];
  __align__(16) unsigned short t[8];
  t[0] = f2bf(a.x); t[1] = f2bf(a.y); t[2] = f2bf(a.z); t[3] = f2bf(a.w);
  t[4] = f2bf(b.x); t[5] = f2bf(b.y); t[6] = f2bf(b.z); t[7] = f2bf(b.w);
  *(uint4*)&Xb[base] = *(const uint4*)t;
}

// -------- macro helpers: named accumulators (forces SROA -> registers) --------
#define FOR_MN(OP) \
  OP(0,0) OP(0,1) OP(0,2) OP(0,3) \
  OP(1,0) OP(1,1) OP(1,2) OP(1,3) \
  OP(2,0) OP(2,1) OP(2,2) OP(2,3) \
  OP(3,0) OP(3,1) OP(3,2) OP(3,3)

#define DECL_ACC(m,n) f32x4 a##m##n = {0.f, 0.f, 0.f, 0.f};

// ------- fused GEMM + rope + relu + bias + tanh + GroupNorm + transpose -------
// bf16 fast path: BK=64 (128B rows -> bank-perfect XOR swizzle: row*32 == 0 mod 32,
// bank group = quad^(l16&7), uniform 2/bank per 16-lane batch; round-3-verified
// 2.6e5 conflicts) + round-4 pipeline (double-buffer, counted vmcnt(8), raw
// barriers so prefetch stays in flight across them). 64KB LDS, 2 blocks/CU.
// fp32 fallback: round-4 BK=32 structure (correct, unoptimized).
template <bool ABF16>
__global__ __launch_bounds__(256, 2) void gemm_fused(const void* __restrict__ Av,
                                                     const unsigned short* __restrict__ Wt,
                                                     const float* __restrict__ hhb,
                                                     const float* __restrict__ gnw,
                                                     const float* __restrict__ gnb,
                                                     float* __restrict__ out) {
  // bf16: A bufs 2x8192 shorts @0 (32KB), B bufs 2x8192 shorts @32768 (32KB).
  // fp32: Af bufs 2x4096 floats @0 (32KB), B bufs 2x4096 shorts @32768 (16KB).
  constexpr int SMEM_BYTES = ABF16 ? 65536 : 49152;
  __shared__ __align__(16) char smem[SMEM_BYTES];
  unsigned short* lsA = (unsigned short*)smem;
  float* lsAf = (float*)smem;
  unsigned short* lsB = (unsigned short*)(smem + 32768);
  float(*lsO)[68] = (float(*)[68])smem;  // epilogue reuse (34.8KB <= SMEM)

  const int tid = threadIdx.x;
  const int wave = tid >> 6;
  const int lane = tid & 63;
  const int quad = lane >> 4;
  const int l16 = lane & 15;
  const int wm = wave >> 1, wn = wave & 1;

  // XCD-aware bijective swizzle: 1024 blocks % 8 XCDs == 0
  const int bid = blockIdx.x;
  const int wg = (bid & 7) * 128 + (bid >> 3);
  const int m0 = (wg >> 4) * 128;  // 64 m-blocks
  const int n0 = (wg & 15) * 128;  // 16 n-blocks

  FOR_MN(DECL_ACC)

  if constexpr (ABF16) {
    // ---- BK=64 staging: tile [128][64] shorts (128B rows); GLD16 covers 8 rows.
    //   lane -> row lane>>3, col8 = lane&7; source col8 ^= (row&7)  (involution)
    const int srow = lane >> 3;
    const int scol = ((lane & 7) ^ (srow & 7)) * 8;
    const unsigned short* gA =
        (const unsigned short*)Av + (size_t)(m0 + wave * 32 + srow) * K_DIM + scol;
    const unsigned short* gB =
        Wt + (size_t)(n0 + wave * 32 + srow) * K_DIM + scol;

    // fragment reads: row R = (wm|wn)*64 + m*16 + l16 (R&7 == l16&7), col kk*32+quad*8
    const int xs0 = (quad * 8) ^ ((l16 & 7) << 3);
    const int xs1 = (32 + quad * 8) ^ ((l16 & 7) << 3);
    const int abase = (wm * 64 + l16) * 64;  // shorts; + m*1024 + xs
    const int bbase = (wn * 64 + l16) * 64;  // shorts; + n*1024 + xs

    auto stage = [&](int d, int koff) {
#pragma unroll
      for (int r = 0; r < 4; ++r)
        GLD16(gA + (size_t)(r * 8) * K_DIM + koff, lsA + d * 8192 + wave * 2048 + r * 512);
#pragma unroll
      for (int r = 0; r < 4; ++r)
        GLD16(gB + (size_t)(r * 8) * K_DIM + koff, lsB + d * 8192 + wave * 2048 + r * 512);
    };

    constexpr int NT = K_DIM / 64;  // 32 K-tiles
    stage(0, 0);                    // prologue: tile 0 in flight
    for (int t = 0; t < NT; ++t) {
      const int cur = t & 1;
      if (t + 1 < NT) {
        stage(cur ^ 1, (t + 1) * 64);  // 8 loads for t+1 stay in flight
        asm volatile("s_waitcnt vmcnt(8)" ::: "memory");  // tile t landed
      } else {
        asm volatile("s_waitcnt vmcnt(0)" ::: "memory");
      }
      __builtin_amdgcn_s_barrier();  // raw: no vmcnt(0) drain of prefetch
      asm volatile("" ::: "memory");

      const unsigned short* pa = lsA + cur * 8192;
      const unsigned short* pb = lsB + cur * 8192;

#define LOAD_AF16(m, XS) bf16x8 af##m = *(const bf16x8*)(const void*)(pa + abase + m * 1024 + XS);
#define LOAD_BF16(n, XS) bf16x8 bfr##n = *(const bf16x8*)(const void*)(pb + bbase + n * 1024 + XS);
#define MFMA_OP(m,n) \
      a##m##n = __builtin_amdgcn_mfma_f32_16x16x32_bf16(af##m, bfr##n, a##m##n, 0, 0, 0);
      {
        LOAD_AF16(0, xs0) LOAD_AF16(1, xs0) LOAD_AF16(2, xs0) LOAD_AF16(3, xs0)
        LOAD_BF16(0, xs0) LOAD_BF16(1, xs0) LOAD_BF16(2, xs0) LOAD_BF16(3, xs0)
        FOR_MN(MFMA_OP)
      }
      {
        LOAD_AF16(0, xs1) LOAD_AF16(1, xs1) LOAD_AF16(2, xs1) LOAD_AF16(3, xs1)
        LOAD_BF16(0, xs1) LOAD_BF16(1, xs1) LOAD_BF16(2, xs1) LOAD_BF16(3, xs1)
        FOR_MN(MFMA_OP)
      }
#undef LOAD_AF16
#undef LOAD_BF16

      // all ds_reads of buf[cur] retired before t+1's stage overwrites it
      asm volatile("s_waitcnt lgkmcnt(0)" ::: "memory");
      __builtin_amdgcn_sched_barrier(0);
      __builtin_amdgcn_s_barrier();
      asm volatile("" ::: "memory");
    }
  } else {
    // ---- fp32 fallback: BK=32 double-buffer (round-4 structure) ----
    const int srow32 = lane >> 3;
    const int scol32 = (((lane & 7) ^ srow32) * 4);
    const int srow16 = lane >> 2;
    const int scol16 = (((lane & 3) ^ (srow16 & 3)) * 8);
    const float* gA32 =
        (const float*)Av + (size_t)(m0 + wave * 32 + srow32) * K_DIM + scol32;
    const unsigned short* gB16 =
        Wt + (size_t)(n0 + wave * 32 + srow16) * K_DIM + scol16;

    const int axs = (quad ^ (l16 & 3)) * 8;
    const int bbase = (wn * 64 + l16) * 32 + axs;
    const int abasef = (wm * 64 + l16) * 32;
    const int u0 = ((2 * quad) ^ (l16 & 7)) * 4;
    const int u1 = ((2 * quad + 1) ^ (l16 & 7)) * 4;

    auto stage = [&](int d, int koff) {
      GLD16(gA32 + koff, lsAf + d * 4096 + wave * 1024);
      GLD16(gA32 + koff + 8 * K_DIM, lsAf + d * 4096 + wave * 1024 + 256);
      GLD16(gA32 + koff + 16 * K_DIM, lsAf + d * 4096 + wave * 1024 + 512);
      GLD16(gA32 + koff + 24 * K_DIM, lsAf + d * 4096 + wave * 1024 + 768);
      GLD16(gB16 + koff, lsB + d * 4096 + wave * 1024);
      GLD16(gB16 + koff + 16 * K_DIM, lsB + d * 4096 + wave * 1024 + 512);
    };

    constexpr int NT = K_DIM / 32;  // 64 K-tiles
    stage(0, 0);
    for (int t = 0; t < NT; ++t) {
      const int cur = t & 1;
      if (t + 1 < NT) {
        stage(cur ^ 1, (t + 1) * 32);
        asm volatile("s_waitcnt vmcnt(6)" ::: "memory");
      } else {
        asm volatile("s_waitcnt vmcnt(0)" ::: "memory");
      }
      __builtin_amdgcn_s_barrier();
      asm volatile("" ::: "memory");

      const float* paf = lsAf + cur * 4096;
      const unsigned short* pb = lsB + cur * 4096;

#define LOAD_AF32(m)                                                      \
      bf16x8 af##m;                                                       \
      { const float* ap_ = paf + abasef + m * 512;                        \
        f32x4 a0_ = *(const f32x4*)(ap_ + u0);                            \
        f32x4 a1_ = *(const f32x4*)(ap_ + u1);                            \
        af##m[0] = (__bf16)a0_[0]; af##m[1] = (__bf16)a0_[1];             \
        af##m[2] = (__bf16)a0_[2]; af##m[3] = (__bf16)a0_[3];             \
        af##m[4] = (__bf16)a1_[0]; af##m[5] = (__bf16)a1_[1];             \
        af##m[6] = (__bf16)a1_[2]; af##m[7] = (__bf16)a1_[3]; }
#define LOAD_BF32(n)                                                      \
      bf16x8 bfr##n = *(const bf16x8*)(const void*)(pb + bbase + n * 512);

      LOAD_AF32(0) LOAD_AF32(1) LOAD_AF32(2) LOAD_AF32(3)
      LOAD_BF32(0) LOAD_BF32(1) LOAD_BF32(2) LOAD_BF32(3)
      FOR_MN(MFMA_OP)
#undef LOAD_AF32
#undef LOAD_BF32

      asm volatile("s_waitcnt lgkmcnt(0)" ::: "memory");
      __builtin_amdgcn_sched_barrier(0);
      __builtin_amdgcn_s_barrier();
      asm volatile("" ::: "memory");
    }
  }

  // ---- epilogue (all fp32); C/D layout: col = l16 (n), row = quad*4 + r (m) ----
  const int c_base = n0 + wn * 64;  // wave's 64 columns == one GroupNorm group
  const int t_base = (m0 & (T_DIM - 1)) + wm * 64;

#define LOADC(n)                                  \
  const int c##n = c_base + n * 16 + l16;         \
  const float hb##n = hhb[c##n];                  \
  const float gw##n = gnw[c##n];                  \
  const float gb##n = gnb[c##n];
  LOADC(0) LOADC(1) LOADC(2) LOADC(3)

  // rope on channels 0..63 (exactly the c_base==0 wave); pair partner is lane^1
  if (c_base == 0) {
#define ROPE_E(n,m,r)                                                   \
    { float v_ = a##m##n[r];                                            \
      float p_ = __shfl_xor(v_, 1, 64);                                 \
      int t_ = t_base + m * 16 + quad * 4 + r;                          \
      float ang_ = (float)t_ * fr_;                                     \
      float s_ = sinf(ang_);                                            \
      float co_ = cosf(ang_);                                           \
      a##m##n[r] = v_ * co_ + sg_ * p_ * s_; }
#define ROPE_M(n,m) ROPE_E(n,m,0) ROPE_E(n,m,1) ROPE_E(n,m,2) ROPE_E(n,m,3)
#define ROPE_N(n)                                                       \
    { int cc_ = n * 16 + l16;                                           \
      int ii_ = cc_ >> 1;                                               \
      float fr_ = expf(-(float)ii_ * 0.28782313662425572f);             \
      float sg_ = (cc_ & 1) ? 1.f : -1.f;                               \
      ROPE_M(n,0) ROPE_M(n,1) ROPE_M(n,2) ROPE_M(n,3) }
    ROPE_N(0) ROPE_N(1) ROPE_N(2) ROPE_N(3)
  }

  // relu -> +bias -> tanh -> GroupNorm (64-ch group == this wave's columns)
#define GN_ROW(m,r)                                                     \
  { float h0_ = tanhf(fmaxf(a##m##0[r], 0.f) + hb0);                    \
    float h1_ = tanhf(fmaxf(a##m##1[r], 0.f) + hb1);                    \
    float h2_ = tanhf(fmaxf(a##m##2[r], 0.f) + hb2);                    \
    float h3_ = tanhf(fmaxf(a##m##3[r], 0.f) + hb3);                    \
    float s1_ = h0_ + h1_ + h2_ + h3_;                                  \
    float s2_ = h0_ * h0_ + h1_ * h1_ + h2_ * h2_ + h3_ * h3_;          \
    s1_ += __shfl_xor(s1_, 1, 64);  s2_ += __shfl_xor(s2_, 1, 64);      \
    s1_ += __shfl_xor(s1_, 2, 64);  s2_ += __shfl_xor(s2_, 2, 64);      \
    s1_ += __shfl_xor(s1_, 4, 64);  s2_ += __shfl_xor(s2_, 4, 64);      \
    s1_ += __shfl_xor(s1_, 8, 64);  s2_ += __shfl_xor(s2_, 8, 64);      \
    float mu_ = s1_ * 0.015625f;                                        \
    float var_ = s2_ * 0.015625f - mu_ * mu_;                           \
    float rs_ = rsqrtf(var_ + 1e-5f);                                   \
    a##m##0[r] = (h0_ - mu_) * rs_ * gw0 + gb0;                         \
    a##m##1[r] = (h1_ - mu_) * rs_ * gw1 + gb1;                         \
    a##m##2[r] = (h2_ - mu_) * rs_ * gw2 + gb2;                         \
    a##m##3[r] = (h3_ - mu_) * rs_ * gw3 + gb3; }
#define GN_M(m) GN_ROW(m,0) GN_ROW(m,1) GN_ROW(m,2) GN_ROW(m,3)
  GN_M(0) GN_M(1) GN_M(2) GN_M(3)

  // ---- transposed store via LDS, two 64-row chunks (wm==h waves own chunk h) ----
  const int bb = m0 >> 12;          // batch
  const int t0 = m0 & (T_DIM - 1);  // t of block row 0
#define ST_MN(m,n)                                                      \
  lsO[wn * 64 + n * 16 + l16][m * 16 + quad * 4 + 0] = a##m##n[0];      \
  lsO[wn * 64 + n * 16 + l16][m * 16 + quad * 4 + 1] = a##m##n[1];      \
  lsO[wn * 64 + n * 16 + l16][m * 16 + quad * 4 + 2] = a##m##n[2];      \
  lsO[wn * 64 + n * 16 + l16][m * 16 + quad * 4 + 3] = a##m##n[3];
#pragma unroll
  for (int h = 0; h < 2; ++h) {
    if (wm == h) {
      FOR_MN(ST_MN)
    }
    __syncthreads();
    // 128 c x 64 t floats = 2048 float4 slots; each thread 8
#pragma unroll
    for (int i = 0; i < 8; ++i) {
      int s = tid + i * 256;
      int cl = s >> 4;
      int t4 = (s & 15) * 4;
      float4 v = *(const float4*)&lsO[cl][t4];
      *(float4*)&out[(size_t)bb * C_DIM * T_DIM + (size_t)(n0 + cl) * T_DIM + t0 + h * 64 + t4] = v;
    }
    __syncthreads();  // before next chunk overwrites lsO
  }
}

// ---------------- S_n passthrough: (2,2048) fp32 after the big tensor ----------------
__global__ __launch_bounds__(256) void copy_sn(const float* __restrict__ src,
                                               float* __restrict__ dst) {
  int i = blockIdx.x * 256 + threadIdx.x;  // 0..4095
  dst[i] = src[i];
}

extern "C" void kernel_launch(void* const* d_in, const int* in_sizes, int n_in,
                              void* d_out, int out_size, void* d_ws, size_t ws_size,
                              hipStream_t stream) {
  const float* X = (const float*)d_in[0];
  const float* Sn = (const float*)d_in[1];
  const float* W = (const float*)d_in[2];
  const float* hhb = (const float*)d_in[3];
  const float* gnw = (const float*)d_in[4];
  const float* gnb = (const float*)d_in[5];
  float* out = (float*)d_out;

  // workspace layout: Wt bf16 [2048][2048] = 8 MB (always);
  // optional Xb bf16 [8192][2048] = 33.5 MB iff workspace is big enough.
  unsigned short* Wt = (unsigned short*)d_ws;
  const size_t wt_bytes = (size_t)C_DIM * K_DIM * 2;      // 8 MB
  const size_t xb_bytes = (size_t)2 * T_DIM * K_DIM * 2;  // 33.5 MB

  transpose_w<<<dim3(32, 32), dim3(256), 0, stream>>>(W, Wt);

  if (ws_size >= wt_bytes + xb_bytes) {
    unsigned short* Xb = Wt + (size_t)C_DIM * K_DIM;
    cvt_x<<<dim3(8192), dim3(256), 0, stream>>>(X, Xb);
    gemm_fused<true><<<dim3(1024), dim3(256), 0, stream>>>(Xb, Wt, hhb, gnw, gnb, out);
  } else {
    gemm_fused<false><<<dim3(1024), dim3(256), 0, stream>>>(X, Wt, hhb, gnw, gnb, out);
  }

  copy_sn<<<dim3(16), dim3(256), 0, stream>>>(Sn, out + (size_t)16777216);
}